// Round 8
// baseline (213.161 us; speedup 1.0000x reference)
//
#include <hip/hip_runtime.h>
#include <hip/hip_fp16.h>

// HyperConv: out = (x + Ax + A^2x + A^3x) / 4, A in COO (rows, cols, vals).
// N=100000 items, E=800000 edges, D=64 features, fp32 in/out.
//
// Round 8: column-sorted buckets. part3 bitonic-sorts each row's bucket by
// col (32-lane shfl sort, one half-wave per row) so all waves sweep x in
// ascending-col order -> GPU-wide sliding window -> per-XCD L2 holds the
// window instead of a random 31% sample of the 12.8MB operand. spmm loop
// unchanged from round 7 (reg-preloaded metadata, dwordx4 fp16 gathers).

#define NI 100000
#define NE 800000
#define DD 64

#define RPB  512                      // rows per bin
#define BINS ((NI + RPB - 1) / RPB)   // 196
#define EPB  1024                     // edges per part1 block
#define P1B  ((NE + EPB - 1) / EPB)   // 782
#define CAP  5120                     // per-bin capacity (mean 4096, 16-sigma)
#define BC   32                       // bucket capacity per row (max deg ~22)

// ---------------------------------------------------------------------------
// part1: bin edges by row>>9 with block-contiguous runs (L2 line-merged).
// payload: .x = (row&511)<<17 | col, .y = val bits
// ---------------------------------------------------------------------------
__global__ __launch_bounds__(256) void part1_k(const int* __restrict__ rows,
                                               const int* __restrict__ cols,
                                               const float* __restrict__ vals,
                                               int* __restrict__ bin_cnt,
                                               int2* __restrict__ binned) {
    __shared__ int hist[BINS], base[BINS], cur[BINS];
    int t = threadIdx.x;
    for (int i = t; i < BINS; i += 256) hist[i] = 0;
    __syncthreads();
    int e0 = blockIdx.x * EPB;
    for (int i = t; i < EPB; i += 256) {
        int e = e0 + i;
        if (e < NE) atomicAdd(&hist[rows[e] >> 9], 1);
    }
    __syncthreads();
    for (int i = t; i < BINS; i += 256) {
        int c = hist[i];
        base[i] = c ? atomicAdd(&bin_cnt[i], c) : 0;
        cur[i] = 0;
    }
    __syncthreads();
    for (int i = t; i < EPB; i += 256) {
        int e = e0 + i;
        if (e < NE) {
            int r = rows[e];
            int b = r >> 9;
            int pos = base[b] + atomicAdd(&cur[b], 1);
            if (pos < CAP)
                binned[(size_t)b * CAP + pos] =
                    make_int2(((r & 511) << 17) | cols[e], __float_as_int(vals[e]));
        }
    }
}

// ---------------------------------------------------------------------------
// part2: one block per bin; bin-local scatter into row buckets; pads each
// row's bucket to EVEN degree with a zero edge so the spmm j-loop steps by 2.
// ---------------------------------------------------------------------------
__global__ __launch_bounds__(256) void part2_k(const int* __restrict__ bin_cnt,
                                               const int2* __restrict__ binned,
                                               int2* __restrict__ bucket,
                                               int* __restrict__ fill) {
    __shared__ int cur[RPB];
    int t = threadIdx.x;
    int b = blockIdx.x;
    for (int i = t; i < RPB; i += 256) cur[i] = 0;
    __syncthreads();
    int cnt = bin_cnt[b];
    if (cnt > CAP) cnt = CAP;
    const int2* src = binned + (size_t)b * CAP;
    for (int i = t; i < cnt; i += 256) {
        int2 e = src[i];
        int rl = e.x >> 17;
        int pos = atomicAdd(&cur[rl], 1);
        if (pos < BC)
            bucket[((size_t)b * RPB + rl) * BC + pos] = make_int2(e.x & 0x1FFFF, e.y);
    }
    __syncthreads();
    for (int i = t; i < RPB; i += 256) {
        int r = b * RPB + i;
        if (r < NI) {
            int c = (cur[i] < BC) ? cur[i] : BC;
            if (c & 1) {
                bucket[((size_t)b * RPB + i) * BC + c] = make_int2(0, 0);
                c++;
            }
            fill[r] = c;
        }
    }
}

// ---------------------------------------------------------------------------
// part3: sort each row's bucket (32 slots) by col, ascending, via a 32-lane
// register bitonic network. One half-wave (lane&31) per row, slot = lane&31.
// Pads beyond deg keyed INT_MAX so they stay at the end (fill unchanged).
// ---------------------------------------------------------------------------
__global__ __launch_bounds__(256) void part3_k(const int* __restrict__ fill,
                                               int2* __restrict__ bucket) {
    int t    = threadIdx.x;
    int l5   = t & 31;                               // slot within row
    int r    = blockIdx.x * 8 + (t >> 5);            // 8 rows per 256-thr block
    int deg  = fill[r];
    int2 e   = bucket[(size_t)r * BC + l5];          // coalesced 256B per row
    int key  = (l5 < deg) ? e.x : 0x7FFFFFFF;
    int val  = e.y;
    int col  = e.x;

    #pragma unroll
    for (int k = 2; k <= 32; k <<= 1) {
        #pragma unroll
        for (int j = k >> 1; j >= 1; j >>= 1) {
            int okey = __shfl_xor(key, j, 64);       // partner within half-wave
            int ocol = __shfl_xor(col, j, 64);
            int oval = __shfl_xor(val, j, 64);
            bool keep_min = ((l5 & j) == 0) == ((l5 & k) == 0);
            bool take_other = keep_min ? (okey < key) : (okey > key);
            if (take_other) { key = okey; col = ocol; val = oval; }
        }
    }
    bucket[(size_t)r * BC + l5] = make_int2(col, val);
}

// ---------------------------------------------------------------------------
// convert: xh = (half)x
// ---------------------------------------------------------------------------
__global__ __launch_bounds__(256) void convert_k(const float4* __restrict__ x,
                                                 __half* __restrict__ xh, int n4) {
    int i = blockIdx.x * 256 + threadIdx.x;
    if (i < n4) {
        float4 v = x[i];
        __half2* dst = (__half2*)(xh + (size_t)i * 4);
        dst[0] = __floats2half2_rn(v.x, v.y);
        dst[1] = __floats2half2_rn(v.z, v.w);
    }
}

// ---------------------------------------------------------------------------
// 8-rows-per-wave gather SpMM with register-preloaded metadata (round 7).
// MODE 0/1: nxt(half) = A * xin(half)
// MODE 2:   outp(f32) = (x0 + s1 + xin + A*xin) * 0.25   (xin == s2)
// ---------------------------------------------------------------------------
template <int MODE>
__global__ __launch_bounds__(256) void spmm_k(const int* __restrict__ fill,
                                              const int2* __restrict__ bucket,
                                              const __half* __restrict__ xin,
                                              __half* __restrict__ nxt,
                                              const float* __restrict__ x0,
                                              const __half* __restrict__ s1,
                                              float* __restrict__ outp) {
    int tid  = threadIdx.x;
    int lane = tid & 63;
    int grp  = lane >> 3;                       // row within wave (0..7)
    int ll   = lane & 7;                        // feature octet index
    int r    = blockIdx.x * 32 + (tid >> 6) * 8 + grp;
    int deg  = fill[r];                         // even (padded), <= BC
    const int2* ep = bucket + (size_t)r * BC;

    int wmax = deg;
    wmax = max(wmax, __shfl_xor(wmax, 8, 64));
    wmax = max(wmax, __shfl_xor(wmax, 16, 64));
    wmax = max(wmax, __shfl_xor(wmax, 32, 64));

    uint4 q0 = *(const uint4*)(ep + 2 * ll);
    uint4 q1 = make_uint4(0u, 0u, 0u, 0u);
    if (wmax > 16) q1 = *(const uint4*)(ep + 16 + 2 * ll);

    float a0 = 0.f, a1 = 0.f, a2 = 0.f, a3 = 0.f;
    float a4 = 0.f, a5 = 0.f, a6 = 0.f, a7 = 0.f;

    for (int j = 0; j < wmax; j += 2) {
        int src = (lane & 56) | ((j >> 1) & 7);
        uint4 q = (j < 16) ? q0 : q1;
        int c0  = __shfl((int)q.x, src, 64);
        int v0i = __shfl((int)q.y, src, 64);
        int c1  = __shfl((int)q.z, src, 64);
        int v1i = __shfl((int)q.w, src, 64);
        if (j < deg) {
            uint4 g0 = *(const uint4*)(xin + (size_t)c0 * DD + 8 * ll);
            uint4 g1 = *(const uint4*)(xin + (size_t)c1 * DD + 8 * ll);
            float v0 = __int_as_float(v0i);
            float v1 = __int_as_float(v1i);
            float2 f;
            f = __half22float2(*(__half2*)&g0.x); a0 += v0 * f.x; a1 += v0 * f.y;
            f = __half22float2(*(__half2*)&g0.y); a2 += v0 * f.x; a3 += v0 * f.y;
            f = __half22float2(*(__half2*)&g0.z); a4 += v0 * f.x; a5 += v0 * f.y;
            f = __half22float2(*(__half2*)&g0.w); a6 += v0 * f.x; a7 += v0 * f.y;
            f = __half22float2(*(__half2*)&g1.x); a0 += v1 * f.x; a1 += v1 * f.y;
            f = __half22float2(*(__half2*)&g1.y); a2 += v1 * f.x; a3 += v1 * f.y;
            f = __half22float2(*(__half2*)&g1.z); a4 += v1 * f.x; a5 += v1 * f.y;
            f = __half22float2(*(__half2*)&g1.w); a6 += v1 * f.x; a7 += v1 * f.y;
        }
    }

    if (MODE == 2) {
        size_t fo = (size_t)r * DD + 8 * ll;
        const float4* xp = (const float4*)(x0 + fo);
        float4 xa = xp[0], xb = xp[1];
        uint4 s1u = *(const uint4*)(s1 + fo);
        uint4 s2u = *(const uint4*)(xin + fo);
        float4 oa, ob;
        float2 f1, f2;
        f1 = __half22float2(*(__half2*)&s1u.x); f2 = __half22float2(*(__half2*)&s2u.x);
        oa.x = (xa.x + f1.x + f2.x + a0) * 0.25f;
        oa.y = (xa.y + f1.y + f2.y + a1) * 0.25f;
        f1 = __half22float2(*(__half2*)&s1u.y); f2 = __half22float2(*(__half2*)&s2u.y);
        oa.z = (xa.z + f1.x + f2.x + a2) * 0.25f;
        oa.w = (xa.w + f1.y + f2.y + a3) * 0.25f;
        f1 = __half22float2(*(__half2*)&s1u.z); f2 = __half22float2(*(__half2*)&s2u.z);
        ob.x = (xb.x + f1.x + f2.x + a4) * 0.25f;
        ob.y = (xb.y + f1.y + f2.y + a5) * 0.25f;
        f1 = __half22float2(*(__half2*)&s1u.w); f2 = __half22float2(*(__half2*)&s2u.w);
        ob.z = (xb.z + f1.x + f2.x + a6) * 0.25f;
        ob.w = (xb.w + f1.y + f2.y + a7) * 0.25f;
        float4* op = (float4*)(outp + fo);
        op[0] = oa;
        op[1] = ob;
    } else {
        uint4 o;
        __half2 h;
        h = __floats2half2_rn(a0, a1); o.x = *(uint*)&h;
        h = __floats2half2_rn(a2, a3); o.y = *(uint*)&h;
        h = __floats2half2_rn(a4, a5); o.z = *(uint*)&h;
        h = __floats2half2_rn(a6, a7); o.w = *(uint*)&h;
        *(uint4*)(nxt + (size_t)r * DD + 8 * ll) = o;
    }
}

// ===========================================================================
// Fallback (round-2 CSR path, fp32, known-good) if ws_size can't fit
// ===========================================================================
#define NB ((NI + 255) / 256)

__global__ __launch_bounds__(256) void init_k(const float4* __restrict__ x,
                                              float4* __restrict__ cur,
                                              float4* __restrict__ acc, int n4) {
    int i = blockIdx.x * 256 + threadIdx.x;
    if (i < n4) { float4 v = x[i]; cur[i] = v; acc[i] = v; }
}

__global__ __launch_bounds__(256) void hist_k(const int* __restrict__ rows,
                                              int* __restrict__ counts) {
    int e = blockIdx.x * 256 + threadIdx.x;
    if (e < NE) atomicAdd(&counts[rows[e]], 1);
}

__global__ __launch_bounds__(256) void scan1_k(const int* __restrict__ counts,
                                               int* __restrict__ bsum) {
    __shared__ int s[256];
    int t = threadIdx.x;
    int i = blockIdx.x * 256 + t;
    s[t] = (i < NI) ? counts[i] : 0;
    __syncthreads();
    for (int off = 128; off > 0; off >>= 1) {
        if (t < off) s[t] += s[t + off];
        __syncthreads();
    }
    if (t == 0) bsum[blockIdx.x] = s[0];
}

__global__ __launch_bounds__(512) void scan2_k(int* __restrict__ bsum) {
    __shared__ int s[512];
    int t = threadIdx.x;
    int v = (t < NB) ? bsum[t] : 0;
    s[t] = v;
    __syncthreads();
    for (int off = 1; off < 512; off <<= 1) {
        int tmp = (t >= off) ? s[t - off] : 0;
        __syncthreads();
        s[t] += tmp;
        __syncthreads();
    }
    if (t < NB) bsum[t] = s[t] - v;
}

__global__ __launch_bounds__(256) void scan3_k(const int* __restrict__ counts,
                                               const int* __restrict__ bsum,
                                               int* __restrict__ rowptr) {
    __shared__ int s[256];
    int t = threadIdx.x;
    int i = blockIdx.x * 256 + t;
    int v = (i < NI) ? counts[i] : 0;
    s[t] = v;
    __syncthreads();
    for (int off = 1; off < 256; off <<= 1) {
        int tmp = (t >= off) ? s[t - off] : 0;
        __syncthreads();
        s[t] += tmp;
        __syncthreads();
    }
    int excl = s[t] - v + bsum[blockIdx.x];
    if (i < NI) rowptr[i] = excl;
    if (i == NI - 1) rowptr[NI] = excl + v;
}

__global__ __launch_bounds__(256) void scatter_k(const int* __restrict__ rows,
                                                 const int* __restrict__ cols,
                                                 const float* __restrict__ vals,
                                                 const int* __restrict__ rowptr,
                                                 int* __restrict__ fillc,
                                                 int2* __restrict__ edges) {
    int e = blockIdx.x * 256 + threadIdx.x;
    if (e < NE) {
        int r = rows[e];
        int pos = rowptr[r] + atomicAdd(&fillc[r], 1);
        edges[pos] = make_int2(cols[e], __float_as_int(vals[e]));
    }
}

__global__ __launch_bounds__(256) void spmm_csr_k(const int* __restrict__ rowptr,
                                                  const int2* __restrict__ edges,
                                                  const float* __restrict__ x,
                                                  float* __restrict__ nxt,
                                                  float* __restrict__ acc,
                                                  int last) {
    int r = __builtin_amdgcn_readfirstlane(blockIdx.x * 4 + (threadIdx.x >> 6));
    int lane = threadIdx.x & 63;
    int beg = rowptr[r];
    int end = rowptr[r + 1];
    float s = 0.f;
    int j = beg;
    for (; j + 3 < end; j += 4) {
        int2 e0 = edges[j], e1 = edges[j + 1], e2 = edges[j + 2], e3 = edges[j + 3];
        float g0 = x[(size_t)e0.x * DD + lane];
        float g1 = x[(size_t)e1.x * DD + lane];
        float g2 = x[(size_t)e2.x * DD + lane];
        float g3 = x[(size_t)e3.x * DD + lane];
        s += __int_as_float(e0.y) * g0; s += __int_as_float(e1.y) * g1;
        s += __int_as_float(e2.y) * g2; s += __int_as_float(e3.y) * g3;
    }
    for (; j < end; ++j) {
        int2 e = edges[j];
        s += __int_as_float(e.y) * x[(size_t)e.x * DD + lane];
    }
    size_t o = (size_t)r * DD + lane;
    if (last) acc[o] = (acc[o] + s) * 0.25f;
    else { nxt[o] = s; acc[o] += s; }
}

extern "C" void kernel_launch(void* const* d_in, const int* in_sizes, int n_in,
                              void* d_out, int out_size, void* d_ws, size_t ws_size,
                              hipStream_t stream) {
    const int*   rows = (const int*)d_in[0];
    const int*   cols = (const int*)d_in[1];
    const float* vals = (const float*)d_in[2];
    const float* x    = (const float*)d_in[3];
    float* outp = (float*)d_out;

    const size_t fbuf  = (size_t)NI * DD * sizeof(float);    // 25.6 MB
    const size_t hbuf  = (size_t)NI * DD * sizeof(__half);   // 12.8 MB
    const int    n4        = NI * DD / 4;
    const int    grid_elem = (n4 + 255) / 256;

    char* wsp = (char*)d_ws;

    // layout: xh | s1h | s2h | bucket(NI*BC*8=25.6MB) | binned(BINS*CAP*8) |
    //         fill(NI*4) | bin_cnt(BINS*4)
    size_t off_xh     = 0;
    size_t off_s1     = off_xh + hbuf;
    size_t off_s2     = off_s1 + hbuf;
    size_t off_bucket = off_s2 + hbuf;
    size_t off_binned = off_bucket + (size_t)NI * BC * 8;
    size_t off_fill   = off_binned + (size_t)BINS * CAP * 8;
    size_t off_bcnt   = off_fill + (size_t)NI * 4;
    size_t need       = off_bcnt + (size_t)BINS * 4;

    if (ws_size >= need) {
        __half* xh      = (__half*)(wsp + off_xh);
        __half* s1h     = (__half*)(wsp + off_s1);
        __half* s2h     = (__half*)(wsp + off_s2);
        int2*   bucket  = (int2*)(wsp + off_bucket);
        int2*   binned  = (int2*)(wsp + off_binned);
        int*    fill    = (int*)(wsp + off_fill);
        int*    bin_cnt = (int*)(wsp + off_bcnt);

        hipMemsetAsync(bin_cnt, 0, BINS * sizeof(int), stream);
        part1_k<<<P1B, 256, 0, stream>>>(rows, cols, vals, bin_cnt, binned);
        part2_k<<<BINS, 256, 0, stream>>>(bin_cnt, binned, bucket, fill);
        part3_k<<<NI / 8, 256, 0, stream>>>(fill, bucket);   // 12500 blocks
        convert_k<<<grid_elem, 256, 0, stream>>>((const float4*)x, xh, n4);

        const int grid_spmm = NI / 32;   // 3125 blocks, 32 rows each, exact
        spmm_k<0><<<grid_spmm, 256, 0, stream>>>(fill, bucket, xh,  s1h, nullptr, nullptr, nullptr);
        spmm_k<1><<<grid_spmm, 256, 0, stream>>>(fill, bucket, s1h, s2h, nullptr, nullptr, nullptr);
        spmm_k<2><<<grid_spmm, 256, 0, stream>>>(fill, bucket, s2h, nullptr, x, s1h, outp);
        return;
    }

    // ---- fallback: round-2 CSR path (fp32) ----
    const int grid_edge = (NE + 255) / 256;
    const int grid_csr  = NI / 4;

    float* bufA   = (float*)wsp;
    float* bufB   = (float*)(wsp + fbuf);
    int2*  edges  = (int2*)(wsp + 2 * fbuf);
    int*   rowptr = (int*)(wsp + 2 * fbuf + (size_t)NE * 8);
    int*   counts = rowptr + (NI + 1);
    int*   bsum   = counts + NI;

    hipMemsetAsync(counts, 0, NI * sizeof(int), stream);
    hist_k<<<grid_edge, 256, 0, stream>>>(rows, counts);
    scan1_k<<<NB, 256, 0, stream>>>(counts, bsum);
    scan2_k<<<1, 512, 0, stream>>>(bsum);
    scan3_k<<<NB, 256, 0, stream>>>(counts, bsum, rowptr);
    hipMemsetAsync(counts, 0, NI * sizeof(int), stream);
    scatter_k<<<grid_edge, 256, 0, stream>>>(rows, cols, vals, rowptr, counts, edges);
    init_k<<<grid_elem, 256, 0, stream>>>((const float4*)x, (float4*)bufA,
                                          (float4*)outp, n4);
    spmm_csr_k<<<grid_csr, 256, 0, stream>>>(rowptr, edges, bufA, bufB, outp, 0);
    spmm_csr_k<<<grid_csr, 256, 0, stream>>>(rowptr, edges, bufB, bufA, outp, 0);
    spmm_csr_k<<<grid_csr, 256, 0, stream>>>(rowptr, edges, bufA, bufB, outp, 1);
}

// Round 9
// 187.125 us; speedup vs baseline: 1.1391x; 1.1391x over previous
//
#include <hip/hip_runtime.h>
#include <hip/hip_fp16.h>

// HyperConv: out = (x + Ax + A^2x + A^3x) / 4, A in COO (rows, cols, vals).
// N=100000 items, E=800000 edges, D=64 features, fp32 in/out.
//
// Round 9: revert round-8's column sort (regression: sort cost ~27us, spmm
// unchanged -- the GPU-wide sliding-window theory was wrong). This is the
// round-7 structure (best measured: 186.1 us):
//  - part1/part2 two-pass partition into padded row buckets (L2 line-merged)
//  - fp16 activations, fp32 accumulate
//  - 8-rows-per-wave spmm, dwordx4 gathers, reg-preloaded shfl-bcast metadata
// Evidence: 4 different spmm inner-loop structures (R4-R8) all ~40-45us/layer
// -> random-line L2-miss/L3 service bound, not bytes/instructions/locality.

#define NI 100000
#define NE 800000
#define DD 64

#define RPB  512                      // rows per bin
#define BINS ((NI + RPB - 1) / RPB)   // 196
#define EPB  1024                     // edges per part1 block
#define P1B  ((NE + EPB - 1) / EPB)   // 782
#define CAP  5120                     // per-bin capacity (mean 4096, 16-sigma)
#define BC   32                       // bucket capacity per row (max deg ~22)

// ---------------------------------------------------------------------------
// part1: bin edges by row>>9 with block-contiguous runs (L2 line-merged).
// payload: .x = (row&511)<<17 | col, .y = val bits
// ---------------------------------------------------------------------------
__global__ __launch_bounds__(256) void part1_k(const int* __restrict__ rows,
                                               const int* __restrict__ cols,
                                               const float* __restrict__ vals,
                                               int* __restrict__ bin_cnt,
                                               int2* __restrict__ binned) {
    __shared__ int hist[BINS], base[BINS], cur[BINS];
    int t = threadIdx.x;
    for (int i = t; i < BINS; i += 256) hist[i] = 0;
    __syncthreads();
    int e0 = blockIdx.x * EPB;
    for (int i = t; i < EPB; i += 256) {
        int e = e0 + i;
        if (e < NE) atomicAdd(&hist[rows[e] >> 9], 1);
    }
    __syncthreads();
    for (int i = t; i < BINS; i += 256) {
        int c = hist[i];
        base[i] = c ? atomicAdd(&bin_cnt[i], c) : 0;
        cur[i] = 0;
    }
    __syncthreads();
    for (int i = t; i < EPB; i += 256) {
        int e = e0 + i;
        if (e < NE) {
            int r = rows[e];
            int b = r >> 9;
            int pos = base[b] + atomicAdd(&cur[b], 1);
            if (pos < CAP)
                binned[(size_t)b * CAP + pos] =
                    make_int2(((r & 511) << 17) | cols[e], __float_as_int(vals[e]));
        }
    }
}

// ---------------------------------------------------------------------------
// part2: one block per bin; bin-local scatter into row buckets; pads each
// row's bucket to EVEN degree with a zero edge so the spmm j-loop steps by 2.
// ---------------------------------------------------------------------------
__global__ __launch_bounds__(256) void part2_k(const int* __restrict__ bin_cnt,
                                               const int2* __restrict__ binned,
                                               int2* __restrict__ bucket,
                                               int* __restrict__ fill) {
    __shared__ int cur[RPB];
    int t = threadIdx.x;
    int b = blockIdx.x;
    for (int i = t; i < RPB; i += 256) cur[i] = 0;
    __syncthreads();
    int cnt = bin_cnt[b];
    if (cnt > CAP) cnt = CAP;
    const int2* src = binned + (size_t)b * CAP;
    for (int i = t; i < cnt; i += 256) {
        int2 e = src[i];
        int rl = e.x >> 17;
        int pos = atomicAdd(&cur[rl], 1);
        if (pos < BC)
            bucket[((size_t)b * RPB + rl) * BC + pos] = make_int2(e.x & 0x1FFFF, e.y);
    }
    __syncthreads();
    for (int i = t; i < RPB; i += 256) {
        int r = b * RPB + i;
        if (r < NI) {
            int c = (cur[i] < BC) ? cur[i] : BC;
            if (c & 1) {
                bucket[((size_t)b * RPB + i) * BC + c] = make_int2(0, 0);
                c++;
            }
            fill[r] = c;
        }
    }
}

// ---------------------------------------------------------------------------
// convert: xh = (half)x
// ---------------------------------------------------------------------------
__global__ __launch_bounds__(256) void convert_k(const float4* __restrict__ x,
                                                 __half* __restrict__ xh, int n4) {
    int i = blockIdx.x * 256 + threadIdx.x;
    if (i < n4) {
        float4 v = x[i];
        __half2* dst = (__half2*)(xh + (size_t)i * 4);
        dst[0] = __floats2half2_rn(v.x, v.y);
        dst[1] = __floats2half2_rn(v.z, v.w);
    }
}

// ---------------------------------------------------------------------------
// 8-rows-per-wave gather SpMM with register-preloaded metadata.
// Block = 256 thr = 4 waves = 32 rows. grp = row in wave, ll = feature octet.
// MODE 0/1: nxt(half) = A * xin(half)
// MODE 2:   outp(f32) = (x0 + s1 + xin + A*xin) * 0.25   (xin == s2)
// ---------------------------------------------------------------------------
template <int MODE>
__global__ __launch_bounds__(256) void spmm_k(const int* __restrict__ fill,
                                              const int2* __restrict__ bucket,
                                              const __half* __restrict__ xin,
                                              __half* __restrict__ nxt,
                                              const float* __restrict__ x0,
                                              const __half* __restrict__ s1,
                                              float* __restrict__ outp) {
    int tid  = threadIdx.x;
    int lane = tid & 63;
    int grp  = lane >> 3;                       // row within wave (0..7)
    int ll   = lane & 7;                        // feature octet index
    int r    = blockIdx.x * 32 + (tid >> 6) * 8 + grp;
    int deg  = fill[r];                         // even (padded), <= BC
    const int2* ep = bucket + (size_t)r * BC;

    int wmax = deg;
    wmax = max(wmax, __shfl_xor(wmax, 8, 64));
    wmax = max(wmax, __shfl_xor(wmax, 16, 64));
    wmax = max(wmax, __shfl_xor(wmax, 32, 64));

    uint4 q0 = *(const uint4*)(ep + 2 * ll);
    uint4 q1 = make_uint4(0u, 0u, 0u, 0u);
    if (wmax > 16) q1 = *(const uint4*)(ep + 16 + 2 * ll);

    float a0 = 0.f, a1 = 0.f, a2 = 0.f, a3 = 0.f;
    float a4 = 0.f, a5 = 0.f, a6 = 0.f, a7 = 0.f;

    for (int j = 0; j < wmax; j += 2) {
        int src = (lane & 56) | ((j >> 1) & 7);
        uint4 q = (j < 16) ? q0 : q1;
        int c0  = __shfl((int)q.x, src, 64);
        int v0i = __shfl((int)q.y, src, 64);
        int c1  = __shfl((int)q.z, src, 64);
        int v1i = __shfl((int)q.w, src, 64);
        if (j < deg) {
            uint4 g0 = *(const uint4*)(xin + (size_t)c0 * DD + 8 * ll);
            uint4 g1 = *(const uint4*)(xin + (size_t)c1 * DD + 8 * ll);
            float v0 = __int_as_float(v0i);
            float v1 = __int_as_float(v1i);
            float2 f;
            f = __half22float2(*(__half2*)&g0.x); a0 += v0 * f.x; a1 += v0 * f.y;
            f = __half22float2(*(__half2*)&g0.y); a2 += v0 * f.x; a3 += v0 * f.y;
            f = __half22float2(*(__half2*)&g0.z); a4 += v0 * f.x; a5 += v0 * f.y;
            f = __half22float2(*(__half2*)&g0.w); a6 += v0 * f.x; a7 += v0 * f.y;
            f = __half22float2(*(__half2*)&g1.x); a0 += v1 * f.x; a1 += v1 * f.y;
            f = __half22float2(*(__half2*)&g1.y); a2 += v1 * f.x; a3 += v1 * f.y;
            f = __half22float2(*(__half2*)&g1.z); a4 += v1 * f.x; a5 += v1 * f.y;
            f = __half22float2(*(__half2*)&g1.w); a6 += v1 * f.x; a7 += v1 * f.y;
        }
    }

    if (MODE == 2) {
        size_t fo = (size_t)r * DD + 8 * ll;
        const float4* xp = (const float4*)(x0 + fo);
        float4 xa = xp[0], xb = xp[1];
        uint4 s1u = *(const uint4*)(s1 + fo);
        uint4 s2u = *(const uint4*)(xin + fo);
        float4 oa, ob;
        float2 f1, f2;
        f1 = __half22float2(*(__half2*)&s1u.x); f2 = __half22float2(*(__half2*)&s2u.x);
        oa.x = (xa.x + f1.x + f2.x + a0) * 0.25f;
        oa.y = (xa.y + f1.y + f2.y + a1) * 0.25f;
        f1 = __half22float2(*(__half2*)&s1u.y); f2 = __half22float2(*(__half2*)&s2u.y);
        oa.z = (xa.z + f1.x + f2.x + a2) * 0.25f;
        oa.w = (xa.w + f1.y + f2.y + a3) * 0.25f;
        f1 = __half22float2(*(__half2*)&s1u.z); f2 = __half22float2(*(__half2*)&s2u.z);
        ob.x = (xb.x + f1.x + f2.x + a4) * 0.25f;
        ob.y = (xb.y + f1.y + f2.y + a5) * 0.25f;
        f1 = __half22float2(*(__half2*)&s1u.w); f2 = __half22float2(*(__half2*)&s2u.w);
        ob.z = (xb.z + f1.x + f2.x + a6) * 0.25f;
        ob.w = (xb.w + f1.y + f2.y + a7) * 0.25f;
        float4* op = (float4*)(outp + fo);
        op[0] = oa;
        op[1] = ob;
    } else {
        uint4 o;
        __half2 h;
        h = __floats2half2_rn(a0, a1); o.x = *(uint*)&h;
        h = __floats2half2_rn(a2, a3); o.y = *(uint*)&h;
        h = __floats2half2_rn(a4, a5); o.z = *(uint*)&h;
        h = __floats2half2_rn(a6, a7); o.w = *(uint*)&h;
        *(uint4*)(nxt + (size_t)r * DD + 8 * ll) = o;
    }
}

// ===========================================================================
// Fallback (round-2 CSR path, fp32, known-good) if ws_size can't fit
// ===========================================================================
#define NB ((NI + 255) / 256)

__global__ __launch_bounds__(256) void init_k(const float4* __restrict__ x,
                                              float4* __restrict__ cur,
                                              float4* __restrict__ acc, int n4) {
    int i = blockIdx.x * 256 + threadIdx.x;
    if (i < n4) { float4 v = x[i]; cur[i] = v; acc[i] = v; }
}

__global__ __launch_bounds__(256) void hist_k(const int* __restrict__ rows,
                                              int* __restrict__ counts) {
    int e = blockIdx.x * 256 + threadIdx.x;
    if (e < NE) atomicAdd(&counts[rows[e]], 1);
}

__global__ __launch_bounds__(256) void scan1_k(const int* __restrict__ counts,
                                               int* __restrict__ bsum) {
    __shared__ int s[256];
    int t = threadIdx.x;
    int i = blockIdx.x * 256 + t;
    s[t] = (i < NI) ? counts[i] : 0;
    __syncthreads();
    for (int off = 128; off > 0; off >>= 1) {
        if (t < off) s[t] += s[t + off];
        __syncthreads();
    }
    if (t == 0) bsum[blockIdx.x] = s[0];
}

__global__ __launch_bounds__(512) void scan2_k(int* __restrict__ bsum) {
    __shared__ int s[512];
    int t = threadIdx.x;
    int v = (t < NB) ? bsum[t] : 0;
    s[t] = v;
    __syncthreads();
    for (int off = 1; off < 512; off <<= 1) {
        int tmp = (t >= off) ? s[t - off] : 0;
        __syncthreads();
        s[t] += tmp;
        __syncthreads();
    }
    if (t < NB) bsum[t] = s[t] - v;
}

__global__ __launch_bounds__(256) void scan3_k(const int* __restrict__ counts,
                                               const int* __restrict__ bsum,
                                               int* __restrict__ rowptr) {
    __shared__ int s[256];
    int t = threadIdx.x;
    int i = blockIdx.x * 256 + t;
    int v = (i < NI) ? counts[i] : 0;
    s[t] = v;
    __syncthreads();
    for (int off = 1; off < 256; off <<= 1) {
        int tmp = (t >= off) ? s[t - off] : 0;
        __syncthreads();
        s[t] += tmp;
        __syncthreads();
    }
    int excl = s[t] - v + bsum[blockIdx.x];
    if (i < NI) rowptr[i] = excl;
    if (i == NI - 1) rowptr[NI] = excl + v;
}

__global__ __launch_bounds__(256) void scatter_k(const int* __restrict__ rows,
                                                 const int* __restrict__ cols,
                                                 const float* __restrict__ vals,
                                                 const int* __restrict__ rowptr,
                                                 int* __restrict__ fillc,
                                                 int2* __restrict__ edges) {
    int e = blockIdx.x * 256 + threadIdx.x;
    if (e < NE) {
        int r = rows[e];
        int pos = rowptr[r] + atomicAdd(&fillc[r], 1);
        edges[pos] = make_int2(cols[e], __float_as_int(vals[e]));
    }
}

__global__ __launch_bounds__(256) void spmm_csr_k(const int* __restrict__ rowptr,
                                                  const int2* __restrict__ edges,
                                                  const float* __restrict__ x,
                                                  float* __restrict__ nxt,
                                                  float* __restrict__ acc,
                                                  int last) {
    int r = __builtin_amdgcn_readfirstlane(blockIdx.x * 4 + (threadIdx.x >> 6));
    int lane = threadIdx.x & 63;
    int beg = rowptr[r];
    int end = rowptr[r + 1];
    float s = 0.f;
    int j = beg;
    for (; j + 3 < end; j += 4) {
        int2 e0 = edges[j], e1 = edges[j + 1], e2 = edges[j + 2], e3 = edges[j + 3];
        float g0 = x[(size_t)e0.x * DD + lane];
        float g1 = x[(size_t)e1.x * DD + lane];
        float g2 = x[(size_t)e2.x * DD + lane];
        float g3 = x[(size_t)e3.x * DD + lane];
        s += __int_as_float(e0.y) * g0; s += __int_as_float(e1.y) * g1;
        s += __int_as_float(e2.y) * g2; s += __int_as_float(e3.y) * g3;
    }
    for (; j < end; ++j) {
        int2 e = edges[j];
        s += __int_as_float(e.y) * x[(size_t)e.x * DD + lane];
    }
    size_t o = (size_t)r * DD + lane;
    if (last) acc[o] = (acc[o] + s) * 0.25f;
    else { nxt[o] = s; acc[o] += s; }
}

extern "C" void kernel_launch(void* const* d_in, const int* in_sizes, int n_in,
                              void* d_out, int out_size, void* d_ws, size_t ws_size,
                              hipStream_t stream) {
    const int*   rows = (const int*)d_in[0];
    const int*   cols = (const int*)d_in[1];
    const float* vals = (const float*)d_in[2];
    const float* x    = (const float*)d_in[3];
    float* outp = (float*)d_out;

    const size_t fbuf  = (size_t)NI * DD * sizeof(float);    // 25.6 MB
    const size_t hbuf  = (size_t)NI * DD * sizeof(__half);   // 12.8 MB
    const int    n4        = NI * DD / 4;
    const int    grid_elem = (n4 + 255) / 256;

    char* wsp = (char*)d_ws;

    // layout: xh | s1h | s2h | bucket(NI*BC*8=25.6MB) | binned(BINS*CAP*8) |
    //         fill(NI*4) | bin_cnt(BINS*4)
    size_t off_xh     = 0;
    size_t off_s1     = off_xh + hbuf;
    size_t off_s2     = off_s1 + hbuf;
    size_t off_bucket = off_s2 + hbuf;
    size_t off_binned = off_bucket + (size_t)NI * BC * 8;
    size_t off_fill   = off_binned + (size_t)BINS * CAP * 8;
    size_t off_bcnt   = off_fill + (size_t)NI * 4;
    size_t need       = off_bcnt + (size_t)BINS * 4;

    if (ws_size >= need) {
        __half* xh      = (__half*)(wsp + off_xh);
        __half* s1h     = (__half*)(wsp + off_s1);
        __half* s2h     = (__half*)(wsp + off_s2);
        int2*   bucket  = (int2*)(wsp + off_bucket);
        int2*   binned  = (int2*)(wsp + off_binned);
        int*    fill    = (int*)(wsp + off_fill);
        int*    bin_cnt = (int*)(wsp + off_bcnt);

        hipMemsetAsync(bin_cnt, 0, BINS * sizeof(int), stream);
        part1_k<<<P1B, 256, 0, stream>>>(rows, cols, vals, bin_cnt, binned);
        part2_k<<<BINS, 256, 0, stream>>>(bin_cnt, binned, bucket, fill);
        convert_k<<<grid_elem, 256, 0, stream>>>((const float4*)x, xh, n4);

        const int grid_spmm = NI / 32;   // 3125 blocks, 32 rows each, exact
        spmm_k<0><<<grid_spmm, 256, 0, stream>>>(fill, bucket, xh,  s1h, nullptr, nullptr, nullptr);
        spmm_k<1><<<grid_spmm, 256, 0, stream>>>(fill, bucket, s1h, s2h, nullptr, nullptr, nullptr);
        spmm_k<2><<<grid_spmm, 256, 0, stream>>>(fill, bucket, s2h, nullptr, x, s1h, outp);
        return;
    }

    // ---- fallback: round-2 CSR path (fp32) ----
    const int grid_edge = (NE + 255) / 256;
    const int grid_csr  = NI / 4;

    float* bufA   = (float*)wsp;
    float* bufB   = (float*)(wsp + fbuf);
    int2*  edges  = (int2*)(wsp + 2 * fbuf);
    int*   rowptr = (int*)(wsp + 2 * fbuf + (size_t)NE * 8);
    int*   counts = rowptr + (NI + 1);
    int*   bsum   = counts + NI;

    hipMemsetAsync(counts, 0, NI * sizeof(int), stream);
    hist_k<<<grid_edge, 256, 0, stream>>>(rows, counts);
    scan1_k<<<NB, 256, 0, stream>>>(counts, bsum);
    scan2_k<<<1, 512, 0, stream>>>(bsum);
    scan3_k<<<NB, 256, 0, stream>>>(counts, bsum, rowptr);
    hipMemsetAsync(counts, 0, NI * sizeof(int), stream);
    scatter_k<<<grid_edge, 256, 0, stream>>>(rows, cols, vals, rowptr, counts, edges);
    init_k<<<grid_elem, 256, 0, stream>>>((const float4*)x, (float4*)bufA,
                                          (float4*)outp, n4);
    spmm_csr_k<<<grid_csr, 256, 0, stream>>>(rowptr, edges, bufA, bufB, outp, 0);
    spmm_csr_k<<<grid_csr, 256, 0, stream>>>(rowptr, edges, bufB, bufA, outp, 0);
    spmm_csr_k<<<grid_csr, 256, 0, stream>>>(rowptr, edges, bufA, bufB, outp, 1);
}